// Round 13
// baseline (252.601 us; speedup 1.0000x reference)
//
#include <hip/hip_runtime.h>
#include <hip/hip_cooperative_groups.h>
#include <math.h>

namespace cg = cooperative_groups;

// Problem constants: B=1, C=64, D=H=W=16, HEADS=4, HD=16
#define CN   262144        // C * 4096 floats per [C, D, H, W] tensor
#define BTP 196            // qkv Bt row stride in bf16
#define PTP 68             // proj Bt row stride in bf16

typedef __attribute__((ext_vector_type(8))) short short8;   // 8 bf16 (4 VGPRs)
typedef __attribute__((ext_vector_type(4))) short short4v;  // 8 B
typedef __attribute__((ext_vector_type(4))) float float4v;  // MFMA C/D

static __device__ __forceinline__ unsigned short f2bf(float f) {
    union { float f; unsigned u; } v; v.f = f;
    unsigned r = (v.u + 0x7FFFu + ((v.u >> 16) & 1u)) >> 16;   // RNE
    return (unsigned short)r;
}

// ---------------------------------------------------------------------------
// Persistent cooperative kernel: 256 blocks x 512 threads (grid <= 256 so the
// cooperative-launch occupancy validation passes under ANY occupancy calc;
// r12's 512-block version failed validation -> launch error -> zero output).
// Stage A: spatial conv (1024 units, 4/block) + weight fusion (72 units)
// Stage B: spectral+QKV MFMA GEMM (384 units, 1-2/block)
// Stage C: retention attention MFMA (512 units, 2/block)
// Stage D: projection MFMA (256 units, 1/block)
__global__ __launch_bounds__(512, 2) void mega_kernel(
        const float* __restrict__ x, const float* __restrict__ gamma,
        const float* __restrict__ w_sp, const float* __restrict__ b_sp,
        const float* __restrict__ w_spec, const float* __restrict__ b_spec,
        const float* __restrict__ w_qkv, const float* __restrict__ b_qkv,
        const float* __restrict__ w_proj, const float* __restrict__ b_proj,
        float* __restrict__ out,
        float* y1,                              // also serves as ao0
        unsigned short* __restrict__ wfb, float* __restrict__ bfv,
        unsigned short* __restrict__ qb, unsigned short* __restrict__ kb,
        unsigned short* __restrict__ vtb,
        float* __restrict__ ao1, float* __restrict__ ao2,
        float* __restrict__ ao3) {
    cg::grid_group grid = cg::this_grid();
    __shared__ __align__(16) unsigned char smem[16512];
    int tid = threadIdx.x;
    int bI  = blockIdx.x;

    // ================= Stage A: conv_sp (1024 units) + wfuse (72) ==========
    {
        float* ws = (float*)smem;                          // 576 f
        float (*red)[256] = (float(*)[256])(smem + 2304);  // 8 x 256 f
        for (int u = bI; u < 1096; u += 256) {
            if (u < 1024) {
                int co = u >> 4, d = u & 15;
                __syncthreads();         // guard ws/red reuse across units
                for (int idx = tid; idx < 576; idx += 512) ws[idx] = w_sp[co * 576 + idx];
                __syncthreads();
                int og  = tid & 63;
                int grp = tid >> 6;
                int h = og >> 2, wq = og & 3;
                float ax = 0.f, ay = 0.f, az = 0.f, aw = 0.f;
                #pragma unroll 4
                for (int c2 = 0; c2 < 8; ++c2) {
                    int ci = grp * 8 + c2;
                    const float* row = x + ci * 4096 + d * 256;
                    const float* wc  = ws + ci * 9;
                    #pragma unroll
                    for (int dh = 0; dh < 3; ++dh) {
                        int hh = h + dh - 1;
                        if (hh < 0 || hh > 15) continue;
                        const float* r = row + hh * 16 + wq * 4;
                        float4 q0 = *(const float4*)r;
                        float lm = (wq > 0) ? r[-1] : 0.f;
                        float rp = (wq < 3) ? r[4]  : 0.f;
                        float wL = wc[dh * 3 + 0], wM = wc[dh * 3 + 1], wR = wc[dh * 3 + 2];
                        ax += wL * lm   + wM * q0.x + wR * q0.y;
                        ay += wL * q0.x + wM * q0.y + wR * q0.z;
                        az += wL * q0.y + wM * q0.z + wR * q0.w;
                        aw += wL * q0.z + wM * q0.w + wR * rp;
                    }
                }
                float4 part = {ax, ay, az, aw};
                *(float4*)&red[grp][og * 4] = part;
                __syncthreads();
                if (tid < 256) {
                    float s = b_sp[co];
                    #pragma unroll
                    for (int g = 0; g < 8; ++g) s += red[g][tid];
                    y1[co * 4096 + d * 256 + tid] = s;
                }
            } else {
                int idx = (u - 1024) * 512 + tid;   // 0..36863
                int oc = idx / 192;
                int r  = idx % 192;                 // = cj*3 + t
                float s = 0.f;
                #pragma unroll 8
                for (int ci = 0; ci < 64; ++ci)
                    s += w_qkv[oc * 64 + ci] * w_spec[ci * 192 + r];
                if (oc < 64) s *= 0.25f;
                wfb[oc * 192 + r] = f2bf(s);
                if (idx < 192) {
                    float t = b_qkv[idx];
                    for (int ci = 0; ci < 64; ++ci) t += w_qkv[idx * 64 + ci] * b_spec[ci];
                    if (idx < 64) t *= 0.25f;
                    bfv[idx] = t;
                }
            }
        }
    }
    grid.sync();

    // ================= Stage B: spectral-conv + QKV MFMA (384 units) =======
    {
        unsigned short* Bt = (unsigned short*)smem;    // [32][BTP] 12.25 KB
        for (int u = bI; u < 384; u += 256) {
            __syncthreads();             // guard Bt reuse across units
            int ocg = u % 3;             // 0=q 1=k 2=v
            int pq  = (u / 3) & 7;
            int d   = u / 24;
            {
                int px  = tid & 31;
                int cig = tid >> 5;      // 0..15 (4 ci each)
                const float* yb = y1 + d * 256 + pq * 32 + px;
                #pragma unroll
                for (int cc = 0; cc < 4; ++cc) {
                    int ci = cig * 4 + cc;
                    const float* yc = yb + ci * 4096;
                    #pragma unroll
                    for (int t = 0; t < 3; ++t) {
                        float v = 0.f;
                        if (!((d == 0 && t == 0) || (d == 15 && t == 2)))
                            v = yc[(t - 1) * 256];
                        Bt[px * BTP + ci * 3 + t] = f2bf(v);
                    }
                }
            }
            int wv = tid >> 6, lane = tid & 63;
            int quad = lane >> 4, l15 = lane & 15;
            int Mt = wv >> 1;            // 0..3 (= head)
            int nt = wv & 1;             // N-tile (16 pos)
            short8 af[6];
            {
                const unsigned short* ab = wfb + (ocg * 64 + Mt * 16 + l15) * 192 + quad * 8;
                #pragma unroll
                for (int ks = 0; ks < 6; ++ks) af[ks] = *(const short8*)(ab + ks * 32);
            }
            float bias[4];
            #pragma unroll
            for (int r = 0; r < 4; ++r) bias[r] = bfv[ocg * 64 + Mt * 16 + quad * 4 + r];
            __syncthreads();
            float4v czero = {0.f, 0.f, 0.f, 0.f};
            float4v acc = czero;
            {
                const unsigned short* brow = Bt + (nt * 16 + l15) * BTP + quad * 8;
                #pragma unroll
                for (int ks = 0; ks < 6; ++ks) {
                    short4v lo = *(const short4v*)(brow + ks * 32);
                    short4v hi = *(const short4v*)(brow + ks * 32 + 4);
                    short8 bf8 = {lo[0], lo[1], lo[2], lo[3], hi[0], hi[1], hi[2], hi[3]};
                    acc = __builtin_amdgcn_mfma_f32_16x16x32_bf16(af[ks], bf8, acc, 0, 0, 0);
                }
            }
            {
                int p = d * 256 + pq * 32 + nt * 16 + l15;
                if (ocg == 2) {
                    int h = (p >> 4) & 15, w0 = p & 15;
                    int kap = 8 * (w0 >> 2) + 4 * (h & 1) + (w0 & 3);
                    unsigned short* dst = vtb + ((Mt * 16 + d) * 8 + (h >> 1)) * 512
                                              + (quad * 4) * 32 + kap;
                    #pragma unroll
                    for (int r = 0; r < 4; ++r) dst[r * 32] = f2bf(acc[r] + bias[r]);
                } else {
                    unsigned short* dst = (ocg == 0 ? qb : kb) + Mt * 65536 + p * 16 + quad * 4;
                    unsigned t0 = (unsigned)f2bf(acc[0] + bias[0])
                                | ((unsigned)f2bf(acc[1] + bias[1]) << 16);
                    unsigned t1 = (unsigned)f2bf(acc[2] + bias[2])
                                | ((unsigned)f2bf(acc[3] + bias[3]) << 16);
                    *(unsigned*)dst = t0;
                    *(unsigned*)(dst + 2) = t1;
                }
            }
        }
    }
    grid.sync();

    // ================= Stage C: retention attention MFMA (512 units) =======
    {
        unsigned short* ksh = (unsigned short*)smem;           // 8 KB
        unsigned short* vsh = ((unsigned short*)smem) + 4096;  // 8 KB
        float* gp = (float*)(smem + 16384);                    // 32 f
        int wv = tid >> 6, lane = tid & 63;
        int quad = lane >> 4, l15 = lane & 15;

        if (tid < 32) {
            float g = 1.f / (1.f + __expf(-gamma[0]));
            gp[tid] = __powf(g, (float)tid);
        }

        for (int u = bI; u < 512; u += 256) {
            int head = u >> 7;           // 4
            int mg   = (u >> 5) & 3;     // 4 m-quarters
            int oct  = u & 31;           // 32 q-octets per head
            int t = oct * 8 + wv;        // tile index (= i*16 + j)
            int i = t >> 4, j = t & 15;

            short8 zero8 = {0, 0, 0, 0, 0, 0, 0, 0};
            float4v czero = {0.f, 0.f, 0.f, 0.f};
            short8 qf = zero8;
            if (quad < 2)
                qf = *(const short8*)(qb + head * 65536 + (t * 16 + l15) * 16 + quad * 8);

            const unsigned short* kbh = kb  + head * 65536 + mg * 4 * 4096;
            const unsigned short* vbh = vtb + head * 65536 + mg * 4 * 4096;
            float4 kpre = ((const float4*)kbh)[tid];
            float4 vpre = ((const float4*)vbh)[tid];

            __syncthreads();             // gp ready / prior unit LDS reads done
            float wd[4];
            #pragma unroll
            for (int r = 0; r < 4; ++r)
                wd[r] = gp[abs(l15 - (quad * 4 + r))] * 1.4426950408889634f;

            float4v O = czero;
            for (int mm = 0; mm < 4; ++mm) {
                int m = mg * 4 + mm;
                __syncthreads();
                ((float4*)ksh)[tid] = kpre;
                ((float4*)vsh)[tid] = vpre;
                __syncthreads();
                if (mm < 3) {
                    kpre = ((const float4*)(kbh + (mm + 1) * 4096))[tid];
                    vpre = ((const float4*)(vbh + (mm + 1) * 4096))[tid];
                }
                int eim = abs(i - m);
                #pragma unroll
                for (int np = 0; np < 8; ++np) {
                    union { unsigned u[4]; short8 s8; } a2u;
                    #pragma unroll
                    for (int s = 0; s < 2; ++s) {
                        int n = np * 2 + s;
                        short8 a1 = zero8;
                        if (quad < 2)
                            a1 = *(const short8*)(ksh + n * 256 + l15 * 16 + quad * 8);
                        float4v d1 = __builtin_amdgcn_mfma_f32_16x16x32_bf16(a1, qf, czero, 0, 0, 0);
                        float smn = gp[eim + abs(j - n)];
                        float e0 = __builtin_amdgcn_exp2f(d1[0] * smn * wd[0]);
                        float e1 = __builtin_amdgcn_exp2f(d1[1] * smn * wd[1]);
                        float e2 = __builtin_amdgcn_exp2f(d1[2] * smn * wd[2]);
                        float e3 = __builtin_amdgcn_exp2f(d1[3] * smn * wd[3]);
                        float sm = e0 + e1 + e2 + e3;
                        sm += __shfl_xor(sm, 16);
                        sm += __shfl_xor(sm, 32);
                        float inv = __builtin_amdgcn_rcpf(sm);
                        union { float f; unsigned u; } p0, p1, p2, p3;
                        p0.f = e0 * inv; p1.f = e1 * inv;
                        p2.f = e2 * inv; p3.f = e3 * inv;
                        a2u.u[s * 2]     = ((p0.u + 0x8000u) >> 16) | ((p1.u + 0x8000u) & 0xFFFF0000u);
                        a2u.u[s * 2 + 1] = ((p2.u + 0x8000u) >> 16) | ((p3.u + 0x8000u) & 0xFFFF0000u);
                    }
                    short8 b2 = *(const short8*)(vsh + np * 512 + l15 * 32 + quad * 8);
                    O = __builtin_amdgcn_mfma_f32_16x16x32_bf16(a2u.s8, b2, O, 0, 0, 0);
                }
            }
            float* aop = (mg == 0) ? y1 : ((mg == 1) ? ao1 : ((mg == 2) ? ao2 : ao3));
            float4 ov = {O[0], O[1], O[2], O[3]};
            *(float4*)(aop + (head * 16 + l15) * 4096 + t * 16 + quad * 4) = ov;
        }
    }
    grid.sync();

    // ================= Stage D: projection MFMA (256 units) ================
    {
        unsigned short* Bt = (unsigned short*)smem;    // [16][PTP] 2.2 KB
        int d   = bI >> 4;
        int p16 = bI & 15;
        __syncthreads();                 // guard smem reuse after stage C
        {   // all 512 threads stage: 2 (px,ci) slots each
            int px = tid & 15, cig = tid >> 4;         // cig 0..31 (2 ci each)
            int gbase = d * 256 + p16 * 16 + px;
            #pragma unroll
            for (int cc = 0; cc < 2; ++cc) {
                int ci = cig * 2 + cc;
                int ga = ci * 4096 + gbase;
                float v = y1[ga] + ao1[ga] + ao2[ga] + ao3[ga];
                Bt[px * PTP + ci] = f2bf(v);
            }
        }
        __syncthreads();
        if (tid < 256) {
            int wv = tid >> 6, lane = tid & 63;        // wv = M-tile
            int quad = lane >> 4, l15 = lane & 15;
            float4v czero = {0.f, 0.f, 0.f, 0.f};
            float4v acc = czero;
            short8 af[2];
            const float* wsrc = w_proj + (wv * 16 + l15) * 64 + quad * 8;
            #pragma unroll
            for (int ks = 0; ks < 2; ++ks) {
                float4 wa = *(const float4*)(wsrc + ks * 32);
                float4 wb = *(const float4*)(wsrc + ks * 32 + 4);
                short8 a8 = {(short)f2bf(wa.x), (short)f2bf(wa.y), (short)f2bf(wa.z),
                             (short)f2bf(wa.w), (short)f2bf(wb.x), (short)f2bf(wb.y),
                             (short)f2bf(wb.z), (short)f2bf(wb.w)};
                af[ks] = a8;
            }
            const unsigned short* brow = Bt + l15 * PTP + quad * 8;
            #pragma unroll
            for (int ks = 0; ks < 2; ++ks) {
                short4v lo = *(const short4v*)(brow + ks * 32);
                short4v hi = *(const short4v*)(brow + ks * 32 + 4);
                short8 bf8 = {lo[0], lo[1], lo[2], lo[3], hi[0], hi[1], hi[2], hi[3]};
                acc = __builtin_amdgcn_mfma_f32_16x16x32_bf16(af[ks], bf8, acc, 0, 0, 0);
            }
            int p = d * 256 + p16 * 16 + l15;
            #pragma unroll
            for (int r = 0; r < 4; ++r) {
                int oc = wv * 16 + quad * 4 + r;
                out[oc * 4096 + p] = acc[r] + b_proj[oc];
            }
        }
    }
}

// ---------------------------------------------------------------------------
extern "C" void kernel_launch(void* const* d_in, const int* in_sizes, int n_in,
                              void* d_out, int out_size, void* d_ws, size_t ws_size,
                              hipStream_t stream) {
    const float* x      = (const float*)d_in[0];
    const float* gamma  = (const float*)d_in[1];
    const float* w_sp   = (const float*)d_in[2];
    const float* b_sp   = (const float*)d_in[3];
    const float* w_spec = (const float*)d_in[4];
    const float* b_spec = (const float*)d_in[5];
    const float* w_qkv  = (const float*)d_in[6];
    const float* b_qkv  = (const float*)d_in[7];
    const float* w_proj = (const float*)d_in[8];
    const float* b_proj = (const float*)d_in[9];
    float* out = (float*)d_out;

    float* ws = (float*)d_ws;
    float* y1  = ws;                         // [64][4096] f32; reused as ao0
    unsigned short* wfb = (unsigned short*)(ws + CN);   // [192][192] bf16
    float* bfv = ws + CN + 20480;            // [192] fused bias f32
    unsigned short* qb  = (unsigned short*)(ws + 2 * CN);            // 512 KB bf16
    unsigned short* kb  = (unsigned short*)(ws + 2 * CN + CN / 2);   // 512 KB bf16
    unsigned short* vtb = (unsigned short*)(ws + 3 * CN);            // 512 KB bf16
    float* ao1 = ws + 3 * CN + CN / 2;       // [64][4096] partial (m 4..7)
    float* ao2 = ws + 4 * CN + CN / 2;       // [64][4096] partial (m 8..11)
    float* ao3 = ws + 5 * CN + CN / 2;       // [64][4096] partial (m 12..15)

    void* args[] = {
        (void*)&x, (void*)&gamma, (void*)&w_sp, (void*)&b_sp,
        (void*)&w_spec, (void*)&b_spec, (void*)&w_qkv, (void*)&b_qkv,
        (void*)&w_proj, (void*)&b_proj, (void*)&out,
        (void*)&y1, (void*)&wfb, (void*)&bfv,
        (void*)&qb, (void*)&kb, (void*)&vtb,
        (void*)&ao1, (void*)&ao2, (void*)&ao3
    };
    hipLaunchCooperativeKernel((const void*)mega_kernel, dim3(256), dim3(512),
                               args, 0, stream);
}

// Round 14
// 134.921 us; speedup vs baseline: 1.8722x; 1.8722x over previous
//
#include <hip/hip_runtime.h>
#include <math.h>

// Problem constants: B=1, C=64, D=H=W=16, HEADS=4, HD=16
#define CN   262144        // C * 4096 floats per [C, D, H, W] tensor
#define BTP 196            // qkv Bt row stride in bf16
#define PTP 68             // proj Bt row stride in bf16

typedef __attribute__((ext_vector_type(8))) short short8;   // 8 bf16 (4 VGPRs)
typedef __attribute__((ext_vector_type(4))) short short4v;  // 8 B
typedef __attribute__((ext_vector_type(4))) float float4v;  // MFMA C/D

static __device__ __forceinline__ unsigned short f2bf(float f) {
    union { float f; unsigned u; } v; v.f = f;
    unsigned r = (v.u + 0x7FFFu + ((v.u >> 16) & 1u)) >> 16;   // RNE
    return (unsigned short)r;
}

// ---------------------------------------------------------------------------
// Stage 0+1 merged dispatch (r11-verified). Blocks 0..1023: spatial conv 3x3.
// Blocks 1024..1095: wfuse (conv_spec folded into qkv weights, exact).
__global__ __launch_bounds__(512) void conv_sp_wfuse_kernel(
        const float* __restrict__ x, const float* __restrict__ w,
        const float* __restrict__ b, float* __restrict__ y,
        const float* __restrict__ w_spec, const float* __restrict__ b_spec,
        const float* __restrict__ w_qkv, const float* __restrict__ b_qkv,
        unsigned short* __restrict__ wfb, float* __restrict__ bfv) {
    if (blockIdx.x >= 1024) {
        int idx = (blockIdx.x - 1024) * 512 + threadIdx.x;   // 0..36863
        int oc = idx / 192;
        int r  = idx % 192;                                  // = cj*3 + t
        float s = 0.f;
        #pragma unroll 8
        for (int ci = 0; ci < 64; ++ci)
            s += w_qkv[oc * 64 + ci] * w_spec[ci * 192 + r];
        if (oc < 64) s *= 0.25f;
        wfb[oc * 192 + r] = f2bf(s);
        if (idx < 192) {
            float t = b_qkv[idx];
            for (int ci = 0; ci < 64; ++ci) t += w_qkv[idx * 64 + ci] * b_spec[ci];
            if (idx < 64) t *= 0.25f;
            bfv[idx] = t;
        }
        return;
    }
    __shared__ float ws[576];
    __shared__ float red[8][256];
    int co = blockIdx.x >> 4;
    int d  = blockIdx.x & 15;
    int tid = threadIdx.x;
    for (int idx = tid; idx < 576; idx += 512) ws[idx] = w[co * 576 + idx];
    __syncthreads();
    int og  = tid & 63;
    int grp = tid >> 6;
    int h = og >> 2, wq = og & 3;
    float ax = 0.f, ay = 0.f, az = 0.f, aw = 0.f;
    #pragma unroll 4
    for (int c2 = 0; c2 < 8; ++c2) {
        int ci = grp * 8 + c2;
        const float* row = x + ci * 4096 + d * 256;
        const float* wc  = ws + ci * 9;
        #pragma unroll
        for (int dh = 0; dh < 3; ++dh) {
            int hh = h + dh - 1;
            if (hh < 0 || hh > 15) continue;
            const float* r = row + hh * 16 + wq * 4;
            float4 q0 = *(const float4*)r;
            float lm = (wq > 0) ? r[-1] : 0.f;
            float rp = (wq < 3) ? r[4]  : 0.f;
            float wL = wc[dh * 3 + 0], wM = wc[dh * 3 + 1], wR = wc[dh * 3 + 2];
            ax += wL * lm   + wM * q0.x + wR * q0.y;
            ay += wL * q0.x + wM * q0.y + wR * q0.z;
            az += wL * q0.y + wM * q0.z + wR * q0.w;
            aw += wL * q0.z + wM * q0.w + wR * rp;
        }
    }
    float4 part = {ax, ay, az, aw};
    *(float4*)&red[grp][og * 4] = part;
    __syncthreads();
    if (tid < 256) {
        float s = b[co];
        #pragma unroll
        for (int g = 0; g < 8; ++g) s += red[g][tid];
        y[co * 4096 + d * 256 + tid] = s;
    }
}

// ---------------------------------------------------------------------------
// Stage 2+3: spectral-conv + QKV as MFMA GEMM (r11-verified).
// Block = (d, pos-eighth, oc-third): 384 blocks. M=64, N=32, K=192.
__global__ __launch_bounds__(512, 2) void qkv_mfma_kernel(
        const float* __restrict__ y1, const unsigned short* __restrict__ wfb,
        const float* __restrict__ bfv,
        unsigned short* __restrict__ qb, unsigned short* __restrict__ kb,
        unsigned short* __restrict__ vtb) {
    __shared__ __align__(16) unsigned short Bt[32 * BTP];    // [pos][k], 12.25 KB
    int bI  = blockIdx.x;            // 384 = 16 d x 8 pq x 3 ocg
    int ocg = bI % 3;                // 0=q 1=k 2=v
    int pq  = (bI / 3) & 7;
    int d   = bI / 24;
    int tid = threadIdx.x;

    {   // stage im2col slab: Bt[px][ci*3+t] = y1[ci][d+t-1][pq*32+px]
        int px  = tid & 31;
        int cig = tid >> 5;          // 0..15 (4 ci each)
        const float* yb = y1 + d * 256 + pq * 32 + px;
        #pragma unroll
        for (int cc = 0; cc < 4; ++cc) {
            int ci = cig * 4 + cc;
            const float* yc = yb + ci * 4096;
            #pragma unroll
            for (int t = 0; t < 3; ++t) {
                float v = 0.f;
                if (!((d == 0 && t == 0) || (d == 15 && t == 2)))
                    v = yc[(t - 1) * 256];
                Bt[px * BTP + ci * 3 + t] = f2bf(v);
            }
        }
    }

    int wv = tid >> 6, lane = tid & 63;
    int quad = lane >> 4, l15 = lane & 15;
    int Mt = wv >> 1;                // 0..3 (= head)
    int nt = wv & 1;                 // N-tile (16 pos)

    short8 af[6];
    {
        const unsigned short* ab = wfb + (ocg * 64 + Mt * 16 + l15) * 192 + quad * 8;
        #pragma unroll
        for (int ks = 0; ks < 6; ++ks) af[ks] = *(const short8*)(ab + ks * 32);
    }
    float bias[4];
    #pragma unroll
    for (int r = 0; r < 4; ++r) bias[r] = bfv[ocg * 64 + Mt * 16 + quad * 4 + r];

    __syncthreads();

    float4v czero = {0.f, 0.f, 0.f, 0.f};
    float4v acc = czero;
    {
        const unsigned short* brow = Bt + (nt * 16 + l15) * BTP + quad * 8;
        #pragma unroll
        for (int ks = 0; ks < 6; ++ks) {
            short4v lo = *(const short4v*)(brow + ks * 32);
            short4v hi = *(const short4v*)(brow + ks * 32 + 4);
            short8 bf8 = {lo[0], lo[1], lo[2], lo[3], hi[0], hi[1], hi[2], hi[3]};
            acc = __builtin_amdgcn_mfma_f32_16x16x32_bf16(af[ks], bf8, acc, 0, 0, 0);
        }
    }

    {   // epilogue: C row = oc_local (quad*4+r), col = pos (l15)
        int p = d * 256 + pq * 32 + nt * 16 + l15;
        if (ocg == 2) {
            int h = (p >> 4) & 15, w0 = p & 15;
            int kap = 8 * (w0 >> 2) + 4 * (h & 1) + (w0 & 3);
            unsigned short* dst = vtb + ((Mt * 16 + d) * 8 + (h >> 1)) * 512
                                      + (quad * 4) * 32 + kap;
            #pragma unroll
            for (int r = 0; r < 4; ++r) dst[r * 32] = f2bf(acc[r] + bias[r]);
        } else {
            unsigned short* dst = (ocg == 0 ? qb : kb) + Mt * 65536 + p * 16 + quad * 4;
            unsigned t0 = (unsigned)f2bf(acc[0] + bias[0])
                        | ((unsigned)f2bf(acc[1] + bias[1]) << 16);
            unsigned t1 = (unsigned)f2bf(acc[2] + bias[2])
                        | ((unsigned)f2bf(acc[3] + bias[3]) << 16);
            *(unsigned*)dst = t0;
            *(unsigned*)(dst + 2) = t1;
        }
    }
}

// ---------------------------------------------------------------------------
// Stage 4: retention attention via MFMA. r14: m-PAIR split (mg 0..7) so the
// block's whole K/V working set (32 KB) stages in ONE shot — 4 global float4
// loads issued together, a single barrier, zero serial slab chain.
// Block = (head, m-pair, q-octet): 1024 blocks x 512 thr, 2 blocks/CU.
__global__ __launch_bounds__(512, 2) void attn_kernel(
        const unsigned short* __restrict__ qb, const unsigned short* __restrict__ kb,
        const unsigned short* __restrict__ vtb, const float* __restrict__ gamma,
        float* __restrict__ aoall) {
    __shared__ __align__(16) unsigned short ksh[2][4096];   // [n][o][d16], 16 KB
    __shared__ __align__(16) unsigned short vsh[2][4096];   // [np][dim][kap], 16 KB
    __shared__ float gp[32];
    int tid = threadIdx.x;
    int bI = blockIdx.x;
    int head = bI >> 8;                 // 4
    int mg   = (bI >> 5) & 7;           // 8 m-pairs
    int oct  = bI & 31;                 // 32 q-octets per head

    if (tid < 32) {
        float g = 1.f / (1.f + __expf(-gamma[0]));
        gp[tid] = __powf(g, (float)tid);
    }

    int wv = tid >> 6, lane = tid & 63;
    int quad = lane >> 4, l15 = lane & 15;
    int t = oct * 8 + wv;               // tile index (= i*16 + j)
    int i = t >> 4, j = t & 15;

    short8 zero8 = {0, 0, 0, 0, 0, 0, 0, 0};
    float4v czero = {0.f, 0.f, 0.f, 0.f};
    short8 qf = zero8;
    if (quad < 2)
        qf = *(const short8*)(qb + head * 65536 + (t * 16 + l15) * 16 + quad * 8);

    // stage BOTH slabs of the m-pair at once (no serial chain)
    const unsigned short* kbh = kb  + head * 65536 + mg * 2 * 4096;
    const unsigned short* vbh = vtb + head * 65536 + mg * 2 * 4096;
    float4 k0 = ((const float4*)kbh)[tid];
    float4 v0 = ((const float4*)vbh)[tid];
    float4 k1 = ((const float4*)(kbh + 4096))[tid];
    float4 v1 = ((const float4*)(vbh + 4096))[tid];
    ((float4*)ksh[0])[tid] = k0;
    ((float4*)vsh[0])[tid] = v0;
    ((float4*)ksh[1])[tid] = k1;
    ((float4*)vsh[1])[tid] = v1;
    __syncthreads();                    // gp + both slabs ready

    float wd[4];
    #pragma unroll
    for (int r = 0; r < 4; ++r)
        wd[r] = gp[abs(l15 - (quad * 4 + r))] * 1.4426950408889634f;   // log2e

    float4v O = czero;
    #pragma unroll
    for (int mm = 0; mm < 2; ++mm) {
        int m = mg * 2 + mm;
        const unsigned short* kk = ksh[mm];
        const unsigned short* vv = vsh[mm];
        int eim = abs(i - m);
        #pragma unroll
        for (int np = 0; np < 8; ++np) {
            union { unsigned u[4]; short8 s8; } a2u;
            #pragma unroll
            for (int s = 0; s < 2; ++s) {
                int n = np * 2 + s;
                short8 a1 = zero8;
                if (quad < 2)
                    a1 = *(const short8*)(kk + n * 256 + l15 * 16 + quad * 8);
                float4v d1 = __builtin_amdgcn_mfma_f32_16x16x32_bf16(a1, qf, czero, 0, 0, 0);
                float smn = gp[eim + abs(j - n)];        // wave-uniform broadcast
                float e0 = __builtin_amdgcn_exp2f(d1[0] * smn * wd[0]);
                float e1 = __builtin_amdgcn_exp2f(d1[1] * smn * wd[1]);
                float e2 = __builtin_amdgcn_exp2f(d1[2] * smn * wd[2]);
                float e3 = __builtin_amdgcn_exp2f(d1[3] * smn * wd[3]);
                float sm = e0 + e1 + e2 + e3;
                sm += __shfl_xor(sm, 16);
                sm += __shfl_xor(sm, 32);
                float inv = __builtin_amdgcn_rcpf(sm);
                union { float f; unsigned u; } p0, p1, p2, p3;
                p0.f = e0 * inv; p1.f = e1 * inv;
                p2.f = e2 * inv; p3.f = e3 * inv;
                a2u.u[s * 2]     = ((p0.u + 0x8000u) >> 16) | ((p1.u + 0x8000u) & 0xFFFF0000u);
                a2u.u[s * 2 + 1] = ((p2.u + 0x8000u) >> 16) | ((p3.u + 0x8000u) & 0xFFFF0000u);
            }
            short8 b2 = *(const short8*)(vv + np * 512 + l15 * 32 + quad * 8);
            O = __builtin_amdgcn_mfma_f32_16x16x32_bf16(a2u.s8, b2, O, 0, 0, 0);
        }
    }

    float* aop = aoall + mg * CN;
    float4 ov = {O[0], O[1], O[2], O[3]};
    *(float4*)(aop + (head * 16 + l15) * 4096 + t * 16 + quad * 4) = ov;
}

// ---------------------------------------------------------------------------
// Stage 5: projection as MFMA GEMM. Block = (d, pos-16th): 256 blocks x 256
// thr. M=64, N=16, K=64. Eight m-pair partials summed during staging.
__global__ __launch_bounds__(256) void proj_mfma_kernel(
        const float* __restrict__ aoall,
        const float* __restrict__ w, const float* __restrict__ b,
        float* __restrict__ out) {
    __shared__ __align__(16) unsigned short Bt[16 * PTP];    // [pos][ci], 2.2 KB
    int d   = blockIdx.x >> 4;
    int p16 = blockIdx.x & 15;
    int tid = threadIdx.x;               // 256

    {   // stage: sum 8 partials -> bf16 Bt[px][ci]
        int px = tid & 15, cig = tid >> 4;        // cig 0..15 (4 ci each)
        int gbase = d * 256 + p16 * 16 + px;
        #pragma unroll
        for (int cc = 0; cc < 4; ++cc) {
            int ci = cig * 4 + cc;
            int ga = ci * 4096 + gbase;
            float v = 0.f;
            #pragma unroll
            for (int k = 0; k < 8; ++k) v += aoall[k * CN + ga];
            Bt[px * PTP + ci] = f2bf(v);
        }
    }
    __syncthreads();

    int wv = tid >> 6, lane = tid & 63;  // 4 waves: wv = M-tile
    int quad = lane >> 4, l15 = lane & 15;
    float4v czero = {0.f, 0.f, 0.f, 0.f};
    float4v acc = czero;

    short8 af[2];
    const float* wsrc = w + (wv * 16 + l15) * 64 + quad * 8;
    #pragma unroll
    for (int ks = 0; ks < 2; ++ks) {
        float4 wa = *(const float4*)(wsrc + ks * 32);
        float4 wb = *(const float4*)(wsrc + ks * 32 + 4);
        short8 a8 = {(short)f2bf(wa.x), (short)f2bf(wa.y), (short)f2bf(wa.z),
                     (short)f2bf(wa.w), (short)f2bf(wb.x), (short)f2bf(wb.y),
                     (short)f2bf(wb.z), (short)f2bf(wb.w)};
        af[ks] = a8;
    }
    const unsigned short* brow = Bt + l15 * PTP + quad * 8;
    #pragma unroll
    for (int ks = 0; ks < 2; ++ks) {
        short4v lo = *(const short4v*)(brow + ks * 32);
        short4v hi = *(const short4v*)(brow + ks * 32 + 4);
        short8 bf8 = {lo[0], lo[1], lo[2], lo[3], hi[0], hi[1], hi[2], hi[3]};
        acc = __builtin_amdgcn_mfma_f32_16x16x32_bf16(af[ks], bf8, acc, 0, 0, 0);
    }

    int p = d * 256 + p16 * 16 + l15;
    #pragma unroll
    for (int r = 0; r < 4; ++r) {
        int oc = wv * 16 + quad * 4 + r;
        out[oc * 4096 + p] = acc[r] + b[oc];
    }
}

// ---------------------------------------------------------------------------
extern "C" void kernel_launch(void* const* d_in, const int* in_sizes, int n_in,
                              void* d_out, int out_size, void* d_ws, size_t ws_size,
                              hipStream_t stream) {
    const float* x      = (const float*)d_in[0];
    const float* gamma  = (const float*)d_in[1];
    const float* w_sp   = (const float*)d_in[2];
    const float* b_sp   = (const float*)d_in[3];
    const float* w_spec = (const float*)d_in[4];
    const float* b_spec = (const float*)d_in[5];
    const float* w_qkv  = (const float*)d_in[6];
    const float* b_qkv  = (const float*)d_in[7];
    const float* w_proj = (const float*)d_in[8];
    const float* b_proj = (const float*)d_in[9];
    float* out = (float*)d_out;

    float* ws = (float*)d_ws;
    float* y1  = ws;                         // [64][4096] f32
    unsigned short* wfb = (unsigned short*)(ws + CN);   // [192][192] bf16
    float* bfv = ws + CN + 20480;            // [192] fused bias f32
    unsigned short* qb  = (unsigned short*)(ws + 2 * CN);            // 512 KB bf16
    unsigned short* kb  = (unsigned short*)(ws + 2 * CN + CN / 2);   // 512 KB bf16
    unsigned short* vtb = (unsigned short*)(ws + 3 * CN);            // 512 KB bf16
    float* aoall = ws + 3 * CN + CN / 2;     // 8 x [64][4096] m-pair partials

    conv_sp_wfuse_kernel<<<1096, 512, 0, stream>>>(x, w_sp, b_sp, y1,
                                                   w_spec, b_spec, w_qkv, b_qkv,
                                                   wfb, bfv);
    qkv_mfma_kernel <<< 384, 512, 0, stream>>>(y1, wfb, bfv, qb, kb, vtb);
    attn_kernel     <<<1024, 512, 0, stream>>>(qb, kb, vtb, gamma, aoall);
    proj_mfma_kernel<<< 256, 256, 0, stream>>>(aoall, w_proj, b_proj, out);
}

// Round 15
// 134.603 us; speedup vs baseline: 1.8766x; 1.0024x over previous
//
#include <hip/hip_runtime.h>
#include <math.h>

// Problem constants: B=1, C=64, D=H=W=16, HEADS=4, HD=16
#define CN   262144        // C * 4096 floats per [C, D, H, W] tensor
#define BTP 196            // qkv Bt row stride in bf16
#define PTP 68             // proj Bt row stride in bf16

typedef __attribute__((ext_vector_type(8))) short short8;   // 8 bf16 (4 VGPRs)
typedef __attribute__((ext_vector_type(4))) short short4v;  // 8 B
typedef __attribute__((ext_vector_type(4))) float float4v;  // MFMA C/D

static __device__ __forceinline__ unsigned short f2bf(float f) {
    union { float f; unsigned u; } v; v.f = f;
    unsigned r = (v.u + 0x7FFFu + ((v.u >> 16) & 1u)) >> 16;   // RNE
    return (unsigned short)r;
}

// ---------------------------------------------------------------------------
// Stage 0+1 merged dispatch. Blocks 0..1023: spatial conv 3x3.
// Blocks 1024..1095: wfuse (conv_spec folded into qkv weights, exact).
// (512,4): 64-VGPR cap -> 4 blocks/CU (r13 mega evidence: stages need ~44).
__global__ __launch_bounds__(512, 4) void conv_sp_wfuse_kernel(
        const float* __restrict__ x, const float* __restrict__ w,
        const float* __restrict__ b, float* __restrict__ y,
        const float* __restrict__ w_spec, const float* __restrict__ b_spec,
        const float* __restrict__ w_qkv, const float* __restrict__ b_qkv,
        unsigned short* __restrict__ wfb, float* __restrict__ bfv) {
    if (blockIdx.x >= 1024) {
        int idx = (blockIdx.x - 1024) * 512 + threadIdx.x;   // 0..36863
        int oc = idx / 192;
        int r  = idx % 192;                                  // = cj*3 + t
        float s = 0.f;
        #pragma unroll 8
        for (int ci = 0; ci < 64; ++ci)
            s += w_qkv[oc * 64 + ci] * w_spec[ci * 192 + r];
        if (oc < 64) s *= 0.25f;
        wfb[oc * 192 + r] = f2bf(s);
        if (idx < 192) {
            float t = b_qkv[idx];
            for (int ci = 0; ci < 64; ++ci) t += w_qkv[idx * 64 + ci] * b_spec[ci];
            if (idx < 64) t *= 0.25f;
            bfv[idx] = t;
        }
        return;
    }
    __shared__ float ws[576];
    __shared__ float red[8][256];
    int co = blockIdx.x >> 4;
    int d  = blockIdx.x & 15;
    int tid = threadIdx.x;
    for (int idx = tid; idx < 576; idx += 512) ws[idx] = w[co * 576 + idx];
    __syncthreads();
    int og  = tid & 63;
    int grp = tid >> 6;
    int h = og >> 2, wq = og & 3;
    float ax = 0.f, ay = 0.f, az = 0.f, aw = 0.f;
    #pragma unroll 4
    for (int c2 = 0; c2 < 8; ++c2) {
        int ci = grp * 8 + c2;
        const float* row = x + ci * 4096 + d * 256;
        const float* wc  = ws + ci * 9;
        #pragma unroll
        for (int dh = 0; dh < 3; ++dh) {
            int hh = h + dh - 1;
            if (hh < 0 || hh > 15) continue;
            const float* r = row + hh * 16 + wq * 4;
            float4 q0 = *(const float4*)r;
            float lm = (wq > 0) ? r[-1] : 0.f;
            float rp = (wq < 3) ? r[4]  : 0.f;
            float wL = wc[dh * 3 + 0], wM = wc[dh * 3 + 1], wR = wc[dh * 3 + 2];
            ax += wL * lm   + wM * q0.x + wR * q0.y;
            ay += wL * q0.x + wM * q0.y + wR * q0.z;
            az += wL * q0.y + wM * q0.z + wR * q0.w;
            aw += wL * q0.z + wM * q0.w + wR * rp;
        }
    }
    float4 part = {ax, ay, az, aw};
    *(float4*)&red[grp][og * 4] = part;
    __syncthreads();
    if (tid < 256) {
        float s = b[co];
        #pragma unroll
        for (int g = 0; g < 8; ++g) s += red[g][tid];
        y[co * 4096 + d * 256 + tid] = s;
    }
}

// ---------------------------------------------------------------------------
// Stage 2+3: spectral-conv + QKV as MFMA GEMM.
// Block = (d, pos-eighth, oc-third): 384 blocks. M=64, N=32, K=192.
// (512,4): 64-VGPR cap -> 4 blocks/CU.
__global__ __launch_bounds__(512, 4) void qkv_mfma_kernel(
        const float* __restrict__ y1, const unsigned short* __restrict__ wfb,
        const float* __restrict__ bfv,
        unsigned short* __restrict__ qb, unsigned short* __restrict__ kb,
        unsigned short* __restrict__ vtb) {
    __shared__ __align__(16) unsigned short Bt[32 * BTP];    // [pos][k], 12.25 KB
    int bI  = blockIdx.x;            // 384 = 16 d x 8 pq x 3 ocg
    int ocg = bI % 3;                // 0=q 1=k 2=v
    int pq  = (bI / 3) & 7;
    int d   = bI / 24;
    int tid = threadIdx.x;

    {   // stage im2col slab: Bt[px][ci*3+t] = y1[ci][d+t-1][pq*32+px]
        int px  = tid & 31;
        int cig = tid >> 5;          // 0..15 (4 ci each)
        const float* yb = y1 + d * 256 + pq * 32 + px;
        #pragma unroll
        for (int cc = 0; cc < 4; ++cc) {
            int ci = cig * 4 + cc;
            const float* yc = yb + ci * 4096;
            #pragma unroll
            for (int t = 0; t < 3; ++t) {
                float v = 0.f;
                if (!((d == 0 && t == 0) || (d == 15 && t == 2)))
                    v = yc[(t - 1) * 256];
                Bt[px * BTP + ci * 3 + t] = f2bf(v);
            }
        }
    }

    int wv = tid >> 6, lane = tid & 63;
    int quad = lane >> 4, l15 = lane & 15;
    int Mt = wv >> 1;                // 0..3 (= head)
    int nt = wv & 1;                 // N-tile (16 pos)

    short8 af[6];
    {
        const unsigned short* ab = wfb + (ocg * 64 + Mt * 16 + l15) * 192 + quad * 8;
        #pragma unroll
        for (int ks = 0; ks < 6; ++ks) af[ks] = *(const short8*)(ab + ks * 32);
    }
    float bias[4];
    #pragma unroll
    for (int r = 0; r < 4; ++r) bias[r] = bfv[ocg * 64 + Mt * 16 + quad * 4 + r];

    __syncthreads();

    float4v czero = {0.f, 0.f, 0.f, 0.f};
    float4v acc = czero;
    {
        const unsigned short* brow = Bt + (nt * 16 + l15) * BTP + quad * 8;
        #pragma unroll
        for (int ks = 0; ks < 6; ++ks) {
            short4v lo = *(const short4v*)(brow + ks * 32);
            short4v hi = *(const short4v*)(brow + ks * 32 + 4);
            short8 bf8 = {lo[0], lo[1], lo[2], lo[3], hi[0], hi[1], hi[2], hi[3]};
            acc = __builtin_amdgcn_mfma_f32_16x16x32_bf16(af[ks], bf8, acc, 0, 0, 0);
        }
    }

    {   // epilogue: C row = oc_local (quad*4+r), col = pos (l15)
        int p = d * 256 + pq * 32 + nt * 16 + l15;
        if (ocg == 2) {
            int h = (p >> 4) & 15, w0 = p & 15;
            int kap = 8 * (w0 >> 2) + 4 * (h & 1) + (w0 & 3);
            unsigned short* dst = vtb + ((Mt * 16 + d) * 8 + (h >> 1)) * 512
                                      + (quad * 4) * 32 + kap;
            #pragma unroll
            for (int r = 0; r < 4; ++r) dst[r * 32] = f2bf(acc[r] + bias[r]);
        } else {
            unsigned short* dst = (ocg == 0 ? qb : kb) + Mt * 65536 + p * 16 + quad * 4;
            unsigned t0 = (unsigned)f2bf(acc[0] + bias[0])
                        | ((unsigned)f2bf(acc[1] + bias[1]) << 16);
            unsigned t1 = (unsigned)f2bf(acc[2] + bias[2])
                        | ((unsigned)f2bf(acc[3] + bias[3]) << 16);
            *(unsigned*)dst = t0;
            *(unsigned*)(dst + 2) = t1;
        }
    }
}

// ---------------------------------------------------------------------------
// Stage 4: retention attention via MFMA, m-pair split (r14 structure).
// (512,4): 64-VGPR cap -> 4 blocks/CU (LDS 32.9 KB x 4 = 131 KB < 160).
__global__ __launch_bounds__(512, 4) void attn_kernel(
        const unsigned short* __restrict__ qb, const unsigned short* __restrict__ kb,
        const unsigned short* __restrict__ vtb, const float* __restrict__ gamma,
        float* __restrict__ aoall) {
    __shared__ __align__(16) unsigned short ksh[2][4096];   // [n][o][d16], 16 KB
    __shared__ __align__(16) unsigned short vsh[2][4096];   // [np][dim][kap], 16 KB
    __shared__ float gp[32];
    int tid = threadIdx.x;
    int bI = blockIdx.x;
    int head = bI >> 8;                 // 4
    int mg   = (bI >> 5) & 7;           // 8 m-pairs
    int oct  = bI & 31;                 // 32 q-octets per head

    if (tid < 32) {
        float g = 1.f / (1.f + __expf(-gamma[0]));
        gp[tid] = __powf(g, (float)tid);
    }

    int wv = tid >> 6, lane = tid & 63;
    int quad = lane >> 4, l15 = lane & 15;
    int t = oct * 8 + wv;               // tile index (= i*16 + j)
    int i = t >> 4, j = t & 15;

    short8 zero8 = {0, 0, 0, 0, 0, 0, 0, 0};
    float4v czero = {0.f, 0.f, 0.f, 0.f};
    short8 qf = zero8;
    if (quad < 2)
        qf = *(const short8*)(qb + head * 65536 + (t * 16 + l15) * 16 + quad * 8);

    // stage BOTH slabs of the m-pair at once (no serial chain)
    const unsigned short* kbh = kb  + head * 65536 + mg * 2 * 4096;
    const unsigned short* vbh = vtb + head * 65536 + mg * 2 * 4096;
    float4 k0 = ((const float4*)kbh)[tid];
    float4 v0 = ((const float4*)vbh)[tid];
    float4 k1 = ((const float4*)(kbh + 4096))[tid];
    float4 v1 = ((const float4*)(vbh + 4096))[tid];
    ((float4*)ksh[0])[tid] = k0;
    ((float4*)vsh[0])[tid] = v0;
    ((float4*)ksh[1])[tid] = k1;
    ((float4*)vsh[1])[tid] = v1;
    __syncthreads();                    // gp + both slabs ready

    float wd[4];
    #pragma unroll
    for (int r = 0; r < 4; ++r)
        wd[r] = gp[abs(l15 - (quad * 4 + r))] * 1.4426950408889634f;   // log2e

    float4v O = czero;
    #pragma unroll
    for (int mm = 0; mm < 2; ++mm) {
        int m = mg * 2 + mm;
        const unsigned short* kk = ksh[mm];
        const unsigned short* vv = vsh[mm];
        int eim = abs(i - m);
        #pragma unroll
        for (int np = 0; np < 8; ++np) {
            union { unsigned u[4]; short8 s8; } a2u;
            #pragma unroll
            for (int s = 0; s < 2; ++s) {
                int n = np * 2 + s;
                short8 a1 = zero8;
                if (quad < 2)
                    a1 = *(const short8*)(kk + n * 256 + l15 * 16 + quad * 8);
                float4v d1 = __builtin_amdgcn_mfma_f32_16x16x32_bf16(a1, qf, czero, 0, 0, 0);
                float smn = gp[eim + abs(j - n)];        // wave-uniform broadcast
                float e0 = __builtin_amdgcn_exp2f(d1[0] * smn * wd[0]);
                float e1 = __builtin_amdgcn_exp2f(d1[1] * smn * wd[1]);
                float e2 = __builtin_amdgcn_exp2f(d1[2] * smn * wd[2]);
                float e3 = __builtin_amdgcn_exp2f(d1[3] * smn * wd[3]);
                float sm = e0 + e1 + e2 + e3;
                sm += __shfl_xor(sm, 16);
                sm += __shfl_xor(sm, 32);
                float inv = __builtin_amdgcn_rcpf(sm);
                union { float f; unsigned u; } p0, p1, p2, p3;
                p0.f = e0 * inv; p1.f = e1 * inv;
                p2.f = e2 * inv; p3.f = e3 * inv;
                a2u.u[s * 2]     = ((p0.u + 0x8000u) >> 16) | ((p1.u + 0x8000u) & 0xFFFF0000u);
                a2u.u[s * 2 + 1] = ((p2.u + 0x8000u) >> 16) | ((p3.u + 0x8000u) & 0xFFFF0000u);
            }
            short8 b2 = *(const short8*)(vv + np * 512 + l15 * 32 + quad * 8);
            O = __builtin_amdgcn_mfma_f32_16x16x32_bf16(a2u.s8, b2, O, 0, 0, 0);
        }
    }

    float* aop = aoall + mg * CN;
    float4 ov = {O[0], O[1], O[2], O[3]};
    *(float4*)(aop + (head * 16 + l15) * 4096 + t * 16 + quad * 4) = ov;
}

// ---------------------------------------------------------------------------
// Stage 5: projection as MFMA GEMM. Block = (d, pos-16th): 256 blocks x 256
// thr. M=64, N=16, K=64. Eight m-pair partials summed during staging.
// (256,8): 64-VGPR cap for max co-residency.
__global__ __launch_bounds__(256, 8) void proj_mfma_kernel(
        const float* __restrict__ aoall,
        const float* __restrict__ w, const float* __restrict__ b,
        float* __restrict__ out) {
    __shared__ __align__(16) unsigned short Bt[16 * PTP];    // [pos][ci], 2.2 KB
    int d   = blockIdx.x >> 4;
    int p16 = blockIdx.x & 15;
    int tid = threadIdx.x;               // 256

    {   // stage: sum 8 partials -> bf16 Bt[px][ci]
        int px = tid & 15, cig = tid >> 4;        // cig 0..15 (4 ci each)
        int gbase = d * 256 + p16 * 16 + px;
        #pragma unroll
        for (int cc = 0; cc < 4; ++cc) {
            int ci = cig * 4 + cc;
            int ga = ci * 4096 + gbase;
            float v = 0.f;
            #pragma unroll
            for (int k = 0; k < 8; ++k) v += aoall[k * CN + ga];
            Bt[px * PTP + ci] = f2bf(v);
        }
    }
    __syncthreads();

    int wv = tid >> 6, lane = tid & 63;  // 4 waves: wv = M-tile
    int quad = lane >> 4, l15 = lane & 15;
    float4v czero = {0.f, 0.f, 0.f, 0.f};
    float4v acc = czero;

    short8 af[2];
    const float* wsrc = w + (wv * 16 + l15) * 64 + quad * 8;
    #pragma unroll
    for (int ks = 0; ks < 2; ++ks) {
        float4 wa = *(const float4*)(wsrc + ks * 32);
        float4 wb = *(const float4*)(wsrc + ks * 32 + 4);
        short8 a8 = {(short)f2bf(wa.x), (short)f2bf(wa.y), (short)f2bf(wa.z),
                     (short)f2bf(wa.w), (short)f2bf(wb.x), (short)f2bf(wb.y),
                     (short)f2bf(wb.z), (short)f2bf(wb.w)};
        af[ks] = a8;
    }
    const unsigned short* brow = Bt + l15 * PTP + quad * 8;
    #pragma unroll
    for (int ks = 0; ks < 2; ++ks) {
        short4v lo = *(const short4v*)(brow + ks * 32);
        short4v hi = *(const short4v*)(brow + ks * 32 + 4);
        short8 bf8 = {lo[0], lo[1], lo[2], lo[3], hi[0], hi[1], hi[2], hi[3]};
        acc = __builtin_amdgcn_mfma_f32_16x16x32_bf16(af[ks], bf8, acc, 0, 0, 0);
    }

    int p = d * 256 + p16 * 16 + l15;
    #pragma unroll
    for (int r = 0; r < 4; ++r) {
        int oc = wv * 16 + quad * 4 + r;
        out[oc * 4096 + p] = acc[r] + b[oc];
    }
}

// ---------------------------------------------------------------------------
extern "C" void kernel_launch(void* const* d_in, const int* in_sizes, int n_in,
                              void* d_out, int out_size, void* d_ws, size_t ws_size,
                              hipStream_t stream) {
    const float* x      = (const float*)d_in[0];
    const float* gamma  = (const float*)d_in[1];
    const float* w_sp   = (const float*)d_in[2];
    const float* b_sp   = (const float*)d_in[3];
    const float* w_spec = (const float*)d_in[4];
    const float* b_spec = (const float*)d_in[5];
    const float* w_qkv  = (const float*)d_in[6];
    const float* b_qkv  = (const float*)d_in[7];
    const float* w_proj = (const float*)d_in[8];
    const float* b_proj = (const float*)d_in[9];
    float* out = (float*)d_out;

    float* ws = (float*)d_ws;
    float* y1  = ws;                         // [64][4096] f32
    unsigned short* wfb = (unsigned short*)(ws + CN);   // [192][192] bf16
    float* bfv = ws + CN + 20480;            // [192] fused bias f32
    unsigned short* qb  = (unsigned short*)(ws + 2 * CN);            // 512 KB bf16
    unsigned short* kb  = (unsigned short*)(ws + 2 * CN + CN / 2);   // 512 KB bf16
    unsigned short* vtb = (unsigned short*)(ws + 3 * CN);            // 512 KB bf16
    float* aoall = ws + 3 * CN + CN / 2;     // 8 x [64][4096] m-pair partials

    conv_sp_wfuse_kernel<<<1096, 512, 0, stream>>>(x, w_sp, b_sp, y1,
                                                   w_spec, b_spec, w_qkv, b_qkv,
                                                   wfb, bfv);
    qkv_mfma_kernel <<< 384, 512, 0, stream>>>(y1, wfb, bfv, qb, kb, vtb);
    attn_kernel     <<<1024, 512, 0, stream>>>(qb, kb, vtb, gamma, aoall);
    proj_mfma_kernel<<< 256, 256, 0, stream>>>(aoall, w_proj, b_proj, out);
}

// Round 16
// 118.137 us; speedup vs baseline: 2.1382x; 1.1394x over previous
//
#include <hip/hip_runtime.h>
#include <math.h>

// Problem constants: B=1, C=64, D=H=W=16, HEADS=4, HD=16
#define CN   262144        // C * 4096 floats per [C, D, H, W] tensor
#define BTP 196            // qkv/conv Bt row stride in bf16
#define PTP 68             // proj Bt row stride in bf16

typedef __attribute__((ext_vector_type(8))) short short8;   // 8 bf16 (4 VGPRs)
typedef __attribute__((ext_vector_type(4))) short short4v;  // 8 B
typedef __attribute__((ext_vector_type(4))) float float4v;  // MFMA C/D

static __device__ __forceinline__ unsigned short f2bf(float f) {
    union { float f; unsigned u; } v; v.f = f;
    unsigned r = (v.u + 0x7FFFu + ((v.u >> 16) & 1u)) >> 16;   // RNE
    return (unsigned short)r;
}

// ---------------------------------------------------------------------------
// Stage 0: weight prep. idx<36864: wsb[dh][co][ci*3+dw] bf16 (spatial conv A).
// idx>=36864: wfuse — conv_spec folded into qkv weights (exact), wfb/bfv.
// 144 blocks x 512 thr.
__global__ __launch_bounds__(512) void wprep_kernel(
        const float* __restrict__ w_sp,
        const float* __restrict__ w_spec, const float* __restrict__ b_spec,
        const float* __restrict__ w_qkv, const float* __restrict__ b_qkv,
        unsigned short* __restrict__ wsb,
        unsigned short* __restrict__ wfb, float* __restrict__ bfv) {
    int idx = blockIdx.x * 512 + threadIdx.x;    // 0..73727
    if (idx < 36864) {
        int dh  = idx / 12288;
        int rem = idx % 12288;
        int co  = rem / 192;
        int kp  = rem % 192;                     // = ci*3 + dw
        int ci = kp / 3, dw = kp % 3;
        wsb[idx] = f2bf(w_sp[co * 576 + ci * 9 + dh * 3 + dw]);
    } else {
        int j = idx - 36864;                     // 0..36863
        int oc = j / 192;
        int r  = j % 192;                        // = cj*3 + t
        float s = 0.f;
        #pragma unroll 8
        for (int ci = 0; ci < 64; ++ci)
            s += w_qkv[oc * 64 + ci] * w_spec[ci * 192 + r];
        if (oc < 64) s *= 0.25f;
        wfb[oc * 192 + r] = f2bf(s);
        if (j < 192) {
            float t = b_qkv[j];
            for (int ci = 0; ci < 64; ++ci) t += w_qkv[j * 64 + ci] * b_spec[ci];
            if (j < 64) t *= 0.25f;
            bfv[j] = t;
        }
    }
}

// ---------------------------------------------------------------------------
// Stage 1: spatial conv 3x3 as MFMA GEMM. Block = (d, h): 256 blocks x 256
// thr. M=64 co, N=16 w, K=576 streamed as 3 dh-chunks of 192 (k'=ci*3+dw).
// Same fragment conventions as the verified qkv_mfma; next chunk's staging
// values are register-prefetched during MFMA. Traffic 295 MB -> ~22 MB.
__global__ __launch_bounds__(256, 4) void conv_sp_mfma_kernel(
        const float* __restrict__ x, const unsigned short* __restrict__ wsb,
        const float* __restrict__ b_sp, float* __restrict__ y1) {
    __shared__ __align__(16) unsigned short Bt[16 * BTP];   // [w][k'], 6.1 KB
    int d = blockIdx.x >> 4;
    int h = blockIdx.x & 15;
    int tid = threadIdx.x;               // 256
    int px = tid & 15, cig = tid >> 4;   // px = w, cig: 16 groups x 4 ci

    float rcur[12], rnxt[12];
    // load chunk dh: rr[cc*3+dw] = x[ci][d][h+dh-1][px+dw-1] (0 if OOB)
    #define LOAD_CHUNK(dh_, rr)                                            \
        {                                                                  \
            int hh = h + (dh_) - 1;                                        \
            _Pragma("unroll")                                              \
            for (int cc = 0; cc < 4; ++cc) {                               \
                int ci = cig * 4 + cc;                                     \
                const float* xr = x + ci * 4096 + d * 256 + hh * 16;       \
                _Pragma("unroll")                                          \
                for (int dw = 0; dw < 3; ++dw) {                           \
                    int ww = px + dw - 1;                                  \
                    float v = 0.f;                                         \
                    if (hh >= 0 && hh <= 15 && ww >= 0 && ww <= 15)        \
                        v = xr[ww];                                        \
                    (rr)[cc * 3 + dw] = v;                                 \
                }                                                          \
            }                                                              \
        }

    LOAD_CHUNK(0, rcur);

    int wv = tid >> 6, lane = tid & 63;  // wv = Mt (co-tile 0..3)
    int quad = lane >> 4, l15 = lane & 15;
    float4v czero = {0.f, 0.f, 0.f, 0.f};
    float4v acc = czero;

    #pragma unroll
    for (int c = 0; c < 3; ++c) {
        __syncthreads();                 // guard Bt reuse across chunks
        #pragma unroll
        for (int cc = 0; cc < 4; ++cc) {
            int ci = cig * 4 + cc;
            Bt[px * BTP + ci * 3 + 0] = f2bf(rcur[cc * 3 + 0]);
            Bt[px * BTP + ci * 3 + 1] = f2bf(rcur[cc * 3 + 1]);
            Bt[px * BTP + ci * 3 + 2] = f2bf(rcur[cc * 3 + 2]);
        }
        __syncthreads();
        if (c < 2) LOAD_CHUNK(c + 1, rnxt);

        const unsigned short* ab = wsb + c * 12288 + (wv * 16 + l15) * 192 + quad * 8;
        const unsigned short* brow = Bt + l15 * BTP + quad * 8;
        #pragma unroll
        for (int ks = 0; ks < 6; ++ks) {
            short8 af = *(const short8*)(ab + ks * 32);
            short4v lo = *(const short4v*)(brow + ks * 32);
            short4v hi = *(const short4v*)(brow + ks * 32 + 4);
            short8 bf8 = {lo[0], lo[1], lo[2], lo[3], hi[0], hi[1], hi[2], hi[3]};
            acc = __builtin_amdgcn_mfma_f32_16x16x32_bf16(af, bf8, acc, 0, 0, 0);
        }
        #pragma unroll
        for (int q2 = 0; q2 < 12; ++q2) rcur[q2] = rnxt[q2];
    }

    // epilogue: C row = co_local (quad*4+r), col = w (l15)
    int p = d * 256 + h * 16 + l15;
    #pragma unroll
    for (int r = 0; r < 4; ++r) {
        int co = wv * 16 + quad * 4 + r;
        y1[co * 4096 + p] = acc[r] + b_sp[co];
    }
    #undef LOAD_CHUNK
}

// ---------------------------------------------------------------------------
// Stage 2+3: spectral-conv + QKV as MFMA GEMM (r15-verified, unchanged).
// Block = (d, pos-eighth, oc-third): 384 blocks. M=64, N=32, K=192.
__global__ __launch_bounds__(512, 4) void qkv_mfma_kernel(
        const float* __restrict__ y1, const unsigned short* __restrict__ wfb,
        const float* __restrict__ bfv,
        unsigned short* __restrict__ qb, unsigned short* __restrict__ kb,
        unsigned short* __restrict__ vtb) {
    __shared__ __align__(16) unsigned short Bt[32 * BTP];    // [pos][k], 12.25 KB
    int bI  = blockIdx.x;            // 384 = 16 d x 8 pq x 3 ocg
    int ocg = bI % 3;                // 0=q 1=k 2=v
    int pq  = (bI / 3) & 7;
    int d   = bI / 24;
    int tid = threadIdx.x;

    {   // stage im2col slab: Bt[px][ci*3+t] = y1[ci][d+t-1][pq*32+px]
        int px  = tid & 31;
        int cig = tid >> 5;          // 0..15 (4 ci each)
        const float* yb = y1 + d * 256 + pq * 32 + px;
        #pragma unroll
        for (int cc = 0; cc < 4; ++cc) {
            int ci = cig * 4 + cc;
            const float* yc = yb + ci * 4096;
            #pragma unroll
            for (int t = 0; t < 3; ++t) {
                float v = 0.f;
                if (!((d == 0 && t == 0) || (d == 15 && t == 2)))
                    v = yc[(t - 1) * 256];
                Bt[px * BTP + ci * 3 + t] = f2bf(v);
            }
        }
    }

    int wv = tid >> 6, lane = tid & 63;
    int quad = lane >> 4, l15 = lane & 15;
    int Mt = wv >> 1;                // 0..3 (= head)
    int nt = wv & 1;                 // N-tile (16 pos)

    short8 af[6];
    {
        const unsigned short* ab = wfb + (ocg * 64 + Mt * 16 + l15) * 192 + quad * 8;
        #pragma unroll
        for (int ks = 0; ks < 6; ++ks) af[ks] = *(const short8*)(ab + ks * 32);
    }
    float bias[4];
    #pragma unroll
    for (int r = 0; r < 4; ++r) bias[r] = bfv[ocg * 64 + Mt * 16 + quad * 4 + r];

    __syncthreads();

    float4v czero = {0.f, 0.f, 0.f, 0.f};
    float4v acc = czero;
    {
        const unsigned short* brow = Bt + (nt * 16 + l15) * BTP + quad * 8;
        #pragma unroll
        for (int ks = 0; ks < 6; ++ks) {
            short4v lo = *(const short4v*)(brow + ks * 32);
            short4v hi = *(const short4v*)(brow + ks * 32 + 4);
            short8 bf8 = {lo[0], lo[1], lo[2], lo[3], hi[0], hi[1], hi[2], hi[3]};
            acc = __builtin_amdgcn_mfma_f32_16x16x32_bf16(af[ks], bf8, acc, 0, 0, 0);
        }
    }

    {   // epilogue: C row = oc_local (quad*4+r), col = pos (l15)
        int p = d * 256 + pq * 32 + nt * 16 + l15;
        if (ocg == 2) {
            int h = (p >> 4) & 15, w0 = p & 15;
            int kap = 8 * (w0 >> 2) + 4 * (h & 1) + (w0 & 3);
            unsigned short* dst = vtb + ((Mt * 16 + d) * 8 + (h >> 1)) * 512
                                      + (quad * 4) * 32 + kap;
            #pragma unroll
            for (int r = 0; r < 4; ++r) dst[r * 32] = f2bf(acc[r] + bias[r]);
        } else {
            unsigned short* dst = (ocg == 0 ? qb : kb) + Mt * 65536 + p * 16 + quad * 4;
            unsigned t0 = (unsigned)f2bf(acc[0] + bias[0])
                        | ((unsigned)f2bf(acc[1] + bias[1]) << 16);
            unsigned t1 = (unsigned)f2bf(acc[2] + bias[2])
                        | ((unsigned)f2bf(acc[3] + bias[3]) << 16);
            *(unsigned*)dst = t0;
            *(unsigned*)(dst + 2) = t1;
        }
    }
}

// ---------------------------------------------------------------------------
// Stage 4: retention attention via MFMA, m-pair split (r15-verified).
__global__ __launch_bounds__(512, 4) void attn_kernel(
        const unsigned short* __restrict__ qb, const unsigned short* __restrict__ kb,
        const unsigned short* __restrict__ vtb, const float* __restrict__ gamma,
        float* __restrict__ aoall) {
    __shared__ __align__(16) unsigned short ksh[2][4096];   // [n][o][d16], 16 KB
    __shared__ __align__(16) unsigned short vsh[2][4096];   // [np][dim][kap], 16 KB
    __shared__ float gp[32];
    int tid = threadIdx.x;
    int bI = blockIdx.x;
    int head = bI >> 8;                 // 4
    int mg   = (bI >> 5) & 7;           // 8 m-pairs
    int oct  = bI & 31;                 // 32 q-octets per head

    if (tid < 32) {
        float g = 1.f / (1.f + __expf(-gamma[0]));
        gp[tid] = __powf(g, (float)tid);
    }

    int wv = tid >> 6, lane = tid & 63;
    int quad = lane >> 4, l15 = lane & 15;
    int t = oct * 8 + wv;               // tile index (= i*16 + j)
    int i = t >> 4, j = t & 15;

    short8 zero8 = {0, 0, 0, 0, 0, 0, 0, 0};
    float4v czero = {0.f, 0.f, 0.f, 0.f};
    short8 qf = zero8;
    if (quad < 2)
        qf = *(const short8*)(qb + head * 65536 + (t * 16 + l15) * 16 + quad * 8);

    // stage BOTH slabs of the m-pair at once (no serial chain)
    const unsigned short* kbh = kb  + head * 65536 + mg * 2 * 4096;
    const unsigned short* vbh = vtb + head * 65536 + mg * 2 * 4096;
    float4 k0 = ((const float4*)kbh)[tid];
    float4 v0 = ((const float4*)vbh)[tid];
    float4 k1 = ((const float4*)(kbh + 4096))[tid];
    float4 v1 = ((const float4*)(vbh + 4096))[tid];
    ((float4*)ksh[0])[tid] = k0;
    ((float4*)vsh[0])[tid] = v0;
    ((float4*)ksh[1])[tid] = k1;
    ((float4*)vsh[1])[tid] = v1;
    __syncthreads();                    // gp + both slabs ready

    float wd[4];
    #pragma unroll
    for (int r = 0; r < 4; ++r)
        wd[r] = gp[abs(l15 - (quad * 4 + r))] * 1.4426950408889634f;   // log2e

    float4v O = czero;
    #pragma unroll
    for (int mm = 0; mm < 2; ++mm) {
        int m = mg * 2 + mm;
        const unsigned short* kk = ksh[mm];
        const unsigned short* vv = vsh[mm];
        int eim = abs(i - m);
        #pragma unroll
        for (int np = 0; np < 8; ++np) {
            union { unsigned u[4]; short8 s8; } a2u;
            #pragma unroll
            for (int s = 0; s < 2; ++s) {
                int n = np * 2 + s;
                short8 a1 = zero8;
                if (quad < 2)
                    a1 = *(const short8*)(kk + n * 256 + l15 * 16 + quad * 8);
                float4v d1 = __builtin_amdgcn_mfma_f32_16x16x32_bf16(a1, qf, czero, 0, 0, 0);
                float smn = gp[eim + abs(j - n)];        // wave-uniform broadcast
                float e0 = __builtin_amdgcn_exp2f(d1[0] * smn * wd[0]);
                float e1 = __builtin_amdgcn_exp2f(d1[1] * smn * wd[1]);
                float e2 = __builtin_amdgcn_exp2f(d1[2] * smn * wd[2]);
                float e3 = __builtin_amdgcn_exp2f(d1[3] * smn * wd[3]);
                float sm = e0 + e1 + e2 + e3;
                sm += __shfl_xor(sm, 16);
                sm += __shfl_xor(sm, 32);
                float inv = __builtin_amdgcn_rcpf(sm);
                union { float f; unsigned u; } p0, p1, p2, p3;
                p0.f = e0 * inv; p1.f = e1 * inv;
                p2.f = e2 * inv; p3.f = e3 * inv;
                a2u.u[s * 2]     = ((p0.u + 0x8000u) >> 16) | ((p1.u + 0x8000u) & 0xFFFF0000u);
                a2u.u[s * 2 + 1] = ((p2.u + 0x8000u) >> 16) | ((p3.u + 0x8000u) & 0xFFFF0000u);
            }
            short8 b2 = *(const short8*)(vv + np * 512 + l15 * 32 + quad * 8);
            O = __builtin_amdgcn_mfma_f32_16x16x32_bf16(a2u.s8, b2, O, 0, 0, 0);
        }
    }

    float* aop = aoall + mg * CN;
    float4 ov = {O[0], O[1], O[2], O[3]};
    *(float4*)(aop + (head * 16 + l15) * 4096 + t * 16 + quad * 4) = ov;
}

// ---------------------------------------------------------------------------
// Stage 5: projection as MFMA GEMM (r15-verified, unchanged).
__global__ __launch_bounds__(256, 8) void proj_mfma_kernel(
        const float* __restrict__ aoall,
        const float* __restrict__ w, const float* __restrict__ b,
        float* __restrict__ out) {
    __shared__ __align__(16) unsigned short Bt[16 * PTP];    // [pos][ci], 2.2 KB
    int d   = blockIdx.x >> 4;
    int p16 = blockIdx.x & 15;
    int tid = threadIdx.x;               // 256

    {   // stage: sum 8 partials -> bf16 Bt[px][ci]
        int px = tid & 15, cig = tid >> 4;        // cig 0..15 (4 ci each)
        int gbase = d * 256 + p16 * 16 + px;
        #pragma unroll
        for (int cc = 0; cc < 4; ++cc) {
            int ci = cig * 4 + cc;
            int ga = ci * 4096 + gbase;
            float v = 0.f;
            #pragma unroll
            for (int k = 0; k < 8; ++k) v += aoall[k * CN + ga];
            Bt[px * PTP + ci] = f2bf(v);
        }
    }
    __syncthreads();

    int wv = tid >> 6, lane = tid & 63;  // 4 waves: wv = M-tile
    int quad = lane >> 4, l15 = lane & 15;
    float4v czero = {0.f, 0.f, 0.f, 0.f};
    float4v acc = czero;

    short8 af[2];
    const float* wsrc = w + (wv * 16 + l15) * 64 + quad * 8;
    #pragma unroll
    for (int ks = 0; ks < 2; ++ks) {
        float4 wa = *(const float4*)(wsrc + ks * 32);
        float4 wb = *(const float4*)(wsrc + ks * 32 + 4);
        short8 a8 = {(short)f2bf(wa.x), (short)f2bf(wa.y), (short)f2bf(wa.z),
                     (short)f2bf(wa.w), (short)f2bf(wb.x), (short)f2bf(wb.y),
                     (short)f2bf(wb.z), (short)f2bf(wb.w)};
        af[ks] = a8;
    }
    const unsigned short* brow = Bt + l15 * PTP + quad * 8;
    #pragma unroll
    for (int ks = 0; ks < 2; ++ks) {
        short4v lo = *(const short4v*)(brow + ks * 32);
        short4v hi = *(const short4v*)(brow + ks * 32 + 4);
        short8 bf8 = {lo[0], lo[1], lo[2], lo[3], hi[0], hi[1], hi[2], hi[3]};
        acc = __builtin_amdgcn_mfma_f32_16x16x32_bf16(af[ks], bf8, acc, 0, 0, 0);
    }

    int p = d * 256 + p16 * 16 + l15;
    #pragma unroll
    for (int r = 0; r < 4; ++r) {
        int oc = wv * 16 + quad * 4 + r;
        out[oc * 4096 + p] = acc[r] + b[oc];
    }
}

// ---------------------------------------------------------------------------
extern "C" void kernel_launch(void* const* d_in, const int* in_sizes, int n_in,
                              void* d_out, int out_size, void* d_ws, size_t ws_size,
                              hipStream_t stream) {
    const float* x      = (const float*)d_in[0];
    const float* gamma  = (const float*)d_in[1];
    const float* w_sp   = (const float*)d_in[2];
    const float* b_sp   = (const float*)d_in[3];
    const float* w_spec = (const float*)d_in[4];
    const float* b_spec = (const float*)d_in[5];
    const float* w_qkv  = (const float*)d_in[6];
    const float* b_qkv  = (const float*)d_in[7];
    const float* w_proj = (const float*)d_in[8];
    const float* b_proj = (const float*)d_in[9];
    float* out = (float*)d_out;

    float* ws = (float*)d_ws;
    float* y1  = ws;                         // [64][4096] f32
    unsigned short* wfb = (unsigned short*)(ws + CN);   // [192][192] bf16
    float* bfv = ws + CN + 20480;            // [192] fused bias f32
    unsigned short* wsb = (unsigned short*)(ws + CN + 24576);  // [3][64][192] bf16
    unsigned short* qb  = (unsigned short*)(ws + 2 * CN);            // 512 KB bf16
    unsigned short* kb  = (unsigned short*)(ws + 2 * CN + CN / 2);   // 512 KB bf16
    unsigned short* vtb = (unsigned short*)(ws + 3 * CN);            // 512 KB bf16
    float* aoall = ws + 3 * CN + CN / 2;     // 8 x [64][4096] m-pair partials

    wprep_kernel       <<< 144, 512, 0, stream>>>(w_sp, w_spec, b_spec,
                                                  w_qkv, b_qkv, wsb, wfb, bfv);
    conv_sp_mfma_kernel<<< 256, 256, 0, stream>>>(x, wsb, b_sp, y1);
    qkv_mfma_kernel    <<< 384, 512, 0, stream>>>(y1, wfb, bfv, qb, kb, vtb);
    attn_kernel        <<<1024, 512, 0, stream>>>(qb, kb, vtb, gamma, aoall);
    proj_mfma_kernel   <<< 256, 256, 0, stream>>>(aoall, w_proj, b_proj, out);
}